// Round 4
// baseline (298.080 us; speedup 1.0000x reference)
//
#include <hip/hip_runtime.h>
#include <hip/hip_bf16.h>

#define B_ 2
#define S_ 2048
#define H_ 1024
#define NH_ 16
#define DH_ 64
#define M_ (B_*S_)      // 4096 rows of q
#define N3_ (3*H_)      // 3072 fused output cols
#define K_ H_           // 1024 reduction dim

typedef __attribute__((ext_vector_type(8))) short bf16x8;
typedef __attribute__((ext_vector_type(4))) short bf16x4;
typedef __attribute__((ext_vector_type(4))) float f32x4;

__device__ __forceinline__ short f2bf(float f) {
  union { float fv; unsigned u; } v; v.fv = f;
  return (short)((v.u + 0x7FFFu + ((v.u >> 16) & 1u)) >> 16);
}

#define MFMA16(a,b,c) __builtin_amdgcn_mfma_f32_16x16x32_bf16((a),(b),(c),0,0,0)

// ---------------- K0a: convert q fp32 -> bf16 ------------------------------
__global__ __launch_bounds__(256) void convert_q(const float* __restrict__ q,
                                                 short* __restrict__ qb) {
  int i = blockIdx.x * blockDim.x + threadIdx.x;
  f32x4 v = ((const f32x4*)q)[i];
  bf16x4 o = { f2bf(v[0]), f2bf(v[1]), f2bf(v[2]), f2bf(v[3]) };
  ((bf16x4*)qb)[i] = o;
}

// ---------------- K0b: transpose+convert W [k][n] fp32 -> Wt [3][n][k] bf16 -
__global__ __launch_bounds__(256) void transpose_w(const float* __restrict__ Wq,
                                                   const float* __restrict__ Wk,
                                                   const float* __restrict__ Wv,
                                                   short* __restrict__ Wt) {
  __shared__ float tile[32][33];
  int w = blockIdx.z;
  const float* W = (w == 0) ? Wq : ((w == 1) ? Wk : Wv);
  int n0 = blockIdx.x * 32, k0 = blockIdx.y * 32;
  int tx = threadIdx.x, ty = threadIdx.y;   // block (32,8)
  for (int i = 0; i < 4; i++)
    tile[ty + 8*i][tx] = W[(size_t)(k0 + ty + 8*i) * H_ + n0 + tx];
  __syncthreads();
  for (int i = 0; i < 4; i++)
    Wt[(size_t)w * H_ * H_ + (size_t)(n0 + ty + 8*i) * H_ + k0 + tx] =
        f2bf(tile[tx][ty + 8*i]);
}

// ---------------- K1: QKV projection GEMM (m97 structure) ------------------
__global__ __launch_bounds__(256) void qkv_gemm(
    const short* __restrict__ qb,   // [4096][1024]
    const short* __restrict__ Wt,   // [3072][1024]
    const float* __restrict__ bq, const float* __restrict__ bk,
    const float* __restrict__ bv,
    short* __restrict__ Qws, short* __restrict__ Kws, short* __restrict__ VT) {
  __shared__ short Wtile[128 * 32];
  __shared__ short Qtile[128 * 32];

  int bidx = blockIdx.x;              // 768 = 32 mtiles * 24 ntiles
  int mt = bidx & 31, nt = bidx >> 5;
  int t = threadIdx.x;
  int wave = t >> 6, lane = t & 63;
  int g = lane >> 4, l15 = lane & 15;
  int nh = (wave & 1) * 64, mh = (wave >> 1) * 64;
  int mblk = mt * 128, nblk = nt * 128;

  int srow = t >> 2, ssub = t & 3;
  const short* wsrc = Wt + (size_t)(nblk + srow) * K_ + ssub * 8;
  const short* qsrc = qb + (size_t)(mblk + srow) * K_ + ssub * 8;
  short* wdst0 = Wtile + wave * 512;
  short* qdst0 = Qtile + wave * 512;

  f32x4 acc[4][4];
#pragma unroll
  for (int i = 0; i < 4; i++)
#pragma unroll
    for (int j = 0; j < 4; j++) acc[i][j] = (f32x4){0.f,0.f,0.f,0.f};

  for (int k0 = 0; k0 < K_; k0 += 32) {
    __builtin_amdgcn_global_load_lds(wsrc + k0,         wdst0,         16, 0, 0);
    __builtin_amdgcn_global_load_lds(wsrc + 64*K_ + k0, wdst0 + 64*32, 16, 0, 0);
    __builtin_amdgcn_global_load_lds(qsrc + k0,         qdst0,         16, 0, 0);
    __builtin_amdgcn_global_load_lds(qsrc + 64*K_ + k0, qdst0 + 64*32, 16, 0, 0);
    __syncthreads();
    bf16x8 af[4], bfr[4];
#pragma unroll
    for (int tn = 0; tn < 4; tn++)
      af[tn] = *(const bf16x8*)(Wtile + (nh + tn*16 + l15) * 32 + g * 8);
#pragma unroll
    for (int tm = 0; tm < 4; tm++)
      bfr[tm] = *(const bf16x8*)(Qtile + (mh + tm*16 + l15) * 32 + g * 8);
#pragma unroll
    for (int tn = 0; tn < 4; tn++)
#pragma unroll
      for (int tm = 0; tm < 4; tm++)
        acc[tn][tm] = MFMA16(af[tn], bfr[tm], acc[tn][tm]);
    __syncthreads();
  }

  int which = nblk >> 10;
  int cbase = nblk & 1023;
  const float* bias = (which == 0) ? bq : ((which == 1) ? bk : bv);

#pragma unroll
  for (int tm = 0; tm < 4; tm++) {
    int m = mblk + mh + tm*16 + l15;
    int b = m >> 11, s = m & 2047;
#pragma unroll
    for (int tn = 0; tn < 4; tn++) {
      int c = cbase + nh + tn*16 + 4*g;
      int head = c >> 6, d0 = c & 63;
      f32x4 bia = *(const f32x4*)(bias + c);
      short o[4];
#pragma unroll
      for (int r = 0; r < 4; r++) o[r] = f2bf(acc[tn][tm][r] + bia[r]);
      if (which == 2) {
        short* base = VT + ((size_t)(b*NH_ + head) * DH_ + d0) * S_ + s;
#pragma unroll
        for (int r = 0; r < 4; r++) base[(size_t)r * S_] = o[r];
      } else {
        short* dst = ((which == 0) ? Qws : Kws)
                   + ((size_t)(b*NH_ + head) * S_ + s) * DH_ + d0;
        bf16x4 o4 = {o[0], o[1], o[2], o[3]};
        *(bf16x4*)dst = o4;
      }
    }
  }
}

// Staging macros: K tile 64 keys x 64 d (8KB), V tile 64 d x 64 keys (8KB).
// LDS[row][granule j] = SRC[row][granule j ^ (row&7)]  (16B granules).
#define STG_K(bufi, kt) do { \
    __builtin_amdgcn_global_load_lds(kSw + (size_t)(kt)*4096,        &Kb[bufi][w*2048],      16, 0, 0); \
    __builtin_amdgcn_global_load_lds(kSw + (size_t)(kt)*4096 + 512,  &Kb[bufi][w*2048+512],  16, 0, 0); \
    __builtin_amdgcn_global_load_lds(kSw + (size_t)(kt)*4096 + 1024, &Kb[bufi][w*2048+1024], 16, 0, 0); \
    __builtin_amdgcn_global_load_lds(kSw + (size_t)(kt)*4096 + 1536, &Kb[bufi][w*2048+1536], 16, 0, 0); \
  } while (0)
#define STG_V(bufi, kt) do { \
    __builtin_amdgcn_global_load_lds(vSw + (size_t)(kt)*64,            &Vb[bufi][w*2048],      16, 0, 0); \
    __builtin_amdgcn_global_load_lds(vSw + (size_t)(kt)*64 +  8*S_,    &Vb[bufi][w*2048+512],  16, 0, 0); \
    __builtin_amdgcn_global_load_lds(vSw + (size_t)(kt)*64 + 16*S_,    &Vb[bufi][w*2048+1024], 16, 0, 0); \
    __builtin_amdgcn_global_load_lds(vSw + (size_t)(kt)*64 + 24*S_,    &Vb[bufi][w*2048+1536], 16, 0, 0); \
  } while (0)

// ---------------- K2a: attn_lcalc — per-q-row 1/sum(exp) -------------------
// 2 waves x 2 q-tiles (32 q-rows/wave, 64/block); contiguous-k-map QK^T:
// K-frag = one swizzled ds_read_b128, reused across both q-tiles.
__global__ __launch_bounds__(128, 2) void attn_lcalc(
    const short* __restrict__ Qws, const short* __restrict__ Kws,
    const float* __restrict__ mask, float* __restrict__ Linv) {
  __shared__ short Kb[2][4096];
  int bid = blockIdx.x;               // 1024 = 32 bh * 32 qt
  int bh = bid >> 5, qt = bid & 31;
  int tid = threadIdx.x;
  int w = tid >> 6, lane = tid & 63;
  int g = lane >> 4, l15 = lane & 15;
  int lr = lane >> 3, l7 = lane & 7;
  int b = bh >> 4;
  int qbase = qt * 64 + w * 32;

  const short* Kh = Kws + (size_t)bh * S_ * DH_;
  const float* mk = mask + b * S_;
  int sw = 8 * (l15 & 7);
  int swc = 8 * (l7 ^ lr);
  const short* kSw = Kh + (size_t)(w*32 + lr) * DH_ + swc;

  const short* qr0 = Qws + (size_t)bh * S_ * DH_ + (size_t)(qbase + l15) * DH_;
  const short* qr1 = qr0 + 16 * DH_;
  bf16x8 q0a = *(const bf16x8*)(qr0 + 8*g), q0b = *(const bf16x8*)(qr0 + 32 + 8*g);
  bf16x8 q1a = *(const bf16x8*)(qr1 + 8*g), q1b = *(const bf16x8*)(qr1 + 32 + 8*g);

  f32x4 ls0 = (f32x4){0.f,0.f,0.f,0.f}, ls1 = (f32x4){0.f,0.f,0.f,0.f};
  STG_K(0, 0);
  __syncthreads();
  int cur = 0;
  for (int kt = 0; kt < 32; kt++) {
    if (kt + 1 < 32) STG_K(cur ^ 1, kt + 1);
    const short* Kt = Kb[cur];
#pragma unroll
    for (int s0i = 0; s0i < 4; s0i++) {
      int s0 = s0i * 16;
      const short* kp = Kt + (s0 + l15) * 64;
      bf16x8 kf0 = *(const bf16x8*)(kp + ((8*g) ^ sw));
      bf16x8 kf1 = *(const bf16x8*)(kp + ((32 + 8*g) ^ sw));
      f32x4 a0 = (f32x4){0.f,0.f,0.f,0.f}, a1 = (f32x4){0.f,0.f,0.f,0.f};
      a0 = MFMA16(kf0, q0a, a0); a0 = MFMA16(kf1, q0b, a0);
      a1 = MFMA16(kf0, q1a, a1); a1 = MFMA16(kf1, q1b, a1);
      f32x4 mv = *(const f32x4*)(mk + kt*64 + s0 + 4*g);
#pragma unroll
      for (int r = 0; r < 4; r++) {
        ls0[r] += __expf(a0[r] * 0.125f * mv[r]);
        ls1[r] += __expf(a1[r] * 0.125f * mv[r]);
      }
    }
    __syncthreads();
    cur ^= 1;
  }
  float l0 = ls0[0]+ls0[1]+ls0[2]+ls0[3];
  float l1 = ls1[0]+ls1[1]+ls1[2]+ls1[3];
  l0 += __shfl_xor(l0, 16); l0 += __shfl_xor(l0, 32);
  l1 += __shfl_xor(l1, 16); l1 += __shfl_xor(l1, 32);
  if (lane < 16) {
    Linv[(size_t)bh * S_ + qbase + lane]      = 1.f / l0;
    Linv[(size_t)bh * S_ + qbase + 16 + lane] = 1.f / l1;
  }
}

// ---------------- K2b: attn_main — recompute, write attn, PV ---------------
__global__ __launch_bounds__(128, 2) void attn_main(
    const short* __restrict__ Qws, const short* __restrict__ Kws,
    const short* __restrict__ VT, const float* __restrict__ mask,
    const float* __restrict__ Linv,
    float* __restrict__ ctx, float* __restrict__ attn) {
  __shared__ short Kb[2][4096];
  __shared__ short Vb[2][4096];
  int bid = blockIdx.x;               // 1024 = 32 bh * 32 qt
  int bh = bid >> 5, qt = bid & 31;
  int tid = threadIdx.x;
  int w = tid >> 6, lane = tid & 63;
  int g = lane >> 4, l15 = lane & 15;
  int lr = lane >> 3, l7 = lane & 7;
  int b = bh >> 4, h = bh & 15;
  int qbase = qt * 64 + w * 32;

  const short* Kh = Kws + (size_t)bh * S_ * DH_;
  const short* Vh = VT  + (size_t)bh * DH_ * S_;
  const float* mk = mask + b * S_;
  int sw = 8 * (l15 & 7);
  int swc = 8 * (l7 ^ lr);
  const short* kSw = Kh + (size_t)(w*32 + lr) * DH_ + swc;
  const short* vSw = Vh + (size_t)(w*32 + lr) * S_  + swc;

  const short* qr0 = Qws + (size_t)bh * S_ * DH_ + (size_t)(qbase + l15) * DH_;
  const short* qr1 = qr0 + 16 * DH_;
  bf16x8 q0a = *(const bf16x8*)(qr0 + 8*g), q0b = *(const bf16x8*)(qr0 + 32 + 8*g);
  bf16x8 q1a = *(const bf16x8*)(qr1 + 8*g), q1b = *(const bf16x8*)(qr1 + 32 + 8*g);

  float linv0 = Linv[(size_t)bh * S_ + qbase + l15];
  float linv1 = Linv[(size_t)bh * S_ + qbase + 16 + l15];
  float* ar0 = attn + ((size_t)bh * S_ + qbase + l15) * (size_t)S_;
  float* ar1 = ar0 + (size_t)16 * S_;

  f32x4 oc0[4], oc1[4];
#pragma unroll
  for (int tv = 0; tv < 4; tv++) {
    oc0[tv] = (f32x4){0.f,0.f,0.f,0.f};
    oc1[tv] = (f32x4){0.f,0.f,0.f,0.f};
  }

  STG_K(0, 0); STG_V(0, 0);
  __syncthreads();
  int cur = 0;
  for (int kt = 0; kt < 32; kt++) {
    if (kt + 1 < 32) { STG_K(cur ^ 1, kt + 1); STG_V(cur ^ 1, kt + 1); }
    const short* Kt = Kb[cur];
    const short* Vt = Vb[cur];
#pragma unroll
    for (int khi = 0; khi < 2; khi++) {
      int kh = khi * 32;
      bf16x8 pa0, pa1;
#pragma unroll
      for (int half = 0; half < 2; half++) {
        int s0 = kh + half * 16;
        const short* kp = Kt + (s0 + l15) * 64;
        bf16x8 kf0 = *(const bf16x8*)(kp + ((8*g) ^ sw));
        bf16x8 kf1 = *(const bf16x8*)(kp + ((32 + 8*g) ^ sw));
        f32x4 a0 = (f32x4){0.f,0.f,0.f,0.f}, a1 = (f32x4){0.f,0.f,0.f,0.f};
        a0 = MFMA16(kf0, q0a, a0); a0 = MFMA16(kf1, q0b, a0);
        a1 = MFMA16(kf0, q1a, a1); a1 = MFMA16(kf1, q1b, a1);
        f32x4 mv = *(const f32x4*)(mk + kt*64 + s0 + 4*g);
        f32x4 p0, p1;
#pragma unroll
        for (int r = 0; r < 4; r++) {
          p0[r] = __expf(a0[r] * 0.125f * mv[r]) * linv0;
          p1[r] = __expf(a1[r] * 0.125f * mv[r]) * linv1;
        }
        *(f32x4*)(ar0 + kt*64 + s0 + 4*g) = p0;
        *(f32x4*)(ar1 + kt*64 + s0 + 4*g) = p1;
#pragma unroll
        for (int r = 0; r < 4; r++) {
          pa0[half*4 + r] = f2bf(p0[r]);
          pa1[half*4 + r] = f2bf(p1[r]);
        }
      }
#pragma unroll
      for (int tv = 0; tv < 4; tv++) {
        const short* vp = Vt + (tv*16 + l15) * 64;
        bf16x4 va = *(const bf16x4*)(vp + ((kh + 4*g) ^ sw));
        bf16x4 vb2 = *(const bf16x4*)(vp + ((kh + 16 + 4*g) ^ sw));
        bf16x8 vf = {va[0],va[1],va[2],va[3], vb2[0],vb2[1],vb2[2],vb2[3]};
        oc0[tv] = MFMA16(pa0, vf, oc0[tv]);
        oc1[tv] = MFMA16(pa1, vf, oc1[tv]);
      }
    }
    __syncthreads();
    cur ^= 1;
  }

  // ctx: tile q = base + 4g + r, d = tv*16 + l15
#pragma unroll
  for (int tv = 0; tv < 4; tv++) {
#pragma unroll
    for (int r = 0; r < 4; r++) {
      int q0 = qbase + 4*g + r;
      int q1 = qbase + 16 + 4*g + r;
      ctx[((size_t)b * S_ + q0) * H_ + h * DH_ + tv*16 + l15] = oc0[tv][r];
      ctx[((size_t)b * S_ + q1) * H_ + h * DH_ + tv*16 + l15] = oc1[tv][r];
    }
  }
}

// ---------------- host ----------------------------------------------------
extern "C" void kernel_launch(void* const* d_in, const int* in_sizes, int n_in,
                              void* d_out, int out_size, void* d_ws, size_t ws_size,
                              hipStream_t stream) {
  const float* q    = (const float*)d_in[0];
  const float* mask = (const float*)d_in[1];
  const float* Wq   = (const float*)d_in[2];
  const float* bq   = (const float*)d_in[3];
  const float* Wk   = (const float*)d_in[4];
  const float* bk   = (const float*)d_in[5];
  const float* Wv   = (const float*)d_in[6];
  const float* bv   = (const float*)d_in[7];

  float* ctx  = (float*)d_out;
  float* attn = ctx + (size_t)B_ * S_ * H_;

  short* qb  = (short*)d_ws;                          // 8 MB
  short* Wt  = qb  + (size_t)M_ * K_;                 // 6 MB
  short* Qws = Wt  + (size_t)N3_ * K_;                // 8 MB
  short* Kws = Qws + (size_t)B_ * NH_ * S_ * DH_;     // 8 MB
  short* VT  = Kws + (size_t)B_ * NH_ * S_ * DH_;     // 8 MB
  float* Linv = (float*)(VT + (size_t)B_ * NH_ * S_ * DH_);  // 256 KB

  convert_q<<<(M_ * K_) / (256 * 4), 256, 0, stream>>>(q, qb);
  transpose_w<<<dim3(32, 32, 3), dim3(32, 8), 0, stream>>>(Wq, Wk, Wv, Wt);
  qkv_gemm<<<768, 256, 0, stream>>>(qb, Wt, bq, bk, bv, Qws, Kws, VT);
  attn_lcalc<<<1024, 128, 0, stream>>>(Qws, Kws, mask, Linv);
  attn_main<<<1024, 128, 0, stream>>>(Qws, Kws, VT, mask, Linv, ctx, attn);
}

// Round 5
// 263.040 us; speedup vs baseline: 1.1332x; 1.1332x over previous
//
#include <hip/hip_runtime.h>
#include <hip/hip_bf16.h>

#define B_ 2
#define S_ 2048
#define H_ 1024
#define NH_ 16
#define DH_ 64
#define M_ (B_*S_)      // 4096 rows of q
#define N3_ (3*H_)      // 3072 fused output cols
#define K_ H_           // 1024 reduction dim

typedef __attribute__((ext_vector_type(8))) short bf16x8;
typedef __attribute__((ext_vector_type(4))) short bf16x4;
typedef __attribute__((ext_vector_type(4))) float f32x4;

__device__ __forceinline__ short f2bf(float f) {
  union { float fv; unsigned u; } v; v.fv = f;
  return (short)((v.u + 0x7FFFu + ((v.u >> 16) & 1u)) >> 16);
}
__device__ __forceinline__ float bf2f(short s) {
  union { unsigned u; float fv; } v; v.u = ((unsigned)(unsigned short)s) << 16;
  return v.fv;
}

#define MFMA16(a,b,c) __builtin_amdgcn_mfma_f32_16x16x32_bf16((a),(b),(c),0,0,0)

// ---------------- K0a: convert q fp32 -> bf16 ------------------------------
__global__ __launch_bounds__(256) void convert_q(const float* __restrict__ q,
                                                 short* __restrict__ qb) {
  int i = blockIdx.x * blockDim.x + threadIdx.x;
  f32x4 v = ((const f32x4*)q)[i];
  bf16x4 o = { f2bf(v[0]), f2bf(v[1]), f2bf(v[2]), f2bf(v[3]) };
  ((bf16x4*)qb)[i] = o;
}

// ---------------- K0b: transpose+convert W [k][n] fp32 -> Wt [3][n][k] bf16 -
__global__ __launch_bounds__(256) void transpose_w(const float* __restrict__ Wq,
                                                   const float* __restrict__ Wk,
                                                   const float* __restrict__ Wv,
                                                   short* __restrict__ Wt) {
  __shared__ float tile[32][33];
  int w = blockIdx.z;
  const float* W = (w == 0) ? Wq : ((w == 1) ? Wk : Wv);
  int n0 = blockIdx.x * 32, k0 = blockIdx.y * 32;
  int tx = threadIdx.x, ty = threadIdx.y;   // block (32,8)
  for (int i = 0; i < 4; i++)
    tile[ty + 8*i][tx] = W[(size_t)(k0 + ty + 8*i) * H_ + n0 + tx];
  __syncthreads();
  for (int i = 0; i < 4; i++)
    Wt[(size_t)w * H_ * H_ + (size_t)(n0 + ty + 8*i) * H_ + k0 + tx] =
        f2bf(tile[tx][ty + 8*i]);
}

// ---------------- K1: QKV projection GEMM (m97 structure) ------------------
__global__ __launch_bounds__(256) void qkv_gemm(
    const short* __restrict__ qb,   // [4096][1024]
    const short* __restrict__ Wt,   // [3072][1024]
    const float* __restrict__ bq, const float* __restrict__ bk,
    const float* __restrict__ bv,
    short* __restrict__ Qws, short* __restrict__ Kws, short* __restrict__ VT) {
  __shared__ short Wtile[128 * 32];
  __shared__ short Qtile[128 * 32];

  int bidx = blockIdx.x;              // 768 = 32 mtiles * 24 ntiles
  int mt = bidx & 31, nt = bidx >> 5;
  int t = threadIdx.x;
  int wave = t >> 6, lane = t & 63;
  int g = lane >> 4, l15 = lane & 15;
  int nh = (wave & 1) * 64, mh = (wave >> 1) * 64;
  int mblk = mt * 128, nblk = nt * 128;

  int srow = t >> 2, ssub = t & 3;
  const short* wsrc = Wt + (size_t)(nblk + srow) * K_ + ssub * 8;
  const short* qsrc = qb + (size_t)(mblk + srow) * K_ + ssub * 8;
  short* wdst0 = Wtile + wave * 512;
  short* qdst0 = Qtile + wave * 512;

  f32x4 acc[4][4];
#pragma unroll
  for (int i = 0; i < 4; i++)
#pragma unroll
    for (int j = 0; j < 4; j++) acc[i][j] = (f32x4){0.f,0.f,0.f,0.f};

  for (int k0 = 0; k0 < K_; k0 += 32) {
    __builtin_amdgcn_global_load_lds(wsrc + k0,         wdst0,         16, 0, 0);
    __builtin_amdgcn_global_load_lds(wsrc + 64*K_ + k0, wdst0 + 64*32, 16, 0, 0);
    __builtin_amdgcn_global_load_lds(qsrc + k0,         qdst0,         16, 0, 0);
    __builtin_amdgcn_global_load_lds(qsrc + 64*K_ + k0, qdst0 + 64*32, 16, 0, 0);
    __syncthreads();
    bf16x8 af[4], bfr[4];
#pragma unroll
    for (int tn = 0; tn < 4; tn++)
      af[tn] = *(const bf16x8*)(Wtile + (nh + tn*16 + l15) * 32 + g * 8);
#pragma unroll
    for (int tm = 0; tm < 4; tm++)
      bfr[tm] = *(const bf16x8*)(Qtile + (mh + tm*16 + l15) * 32 + g * 8);
#pragma unroll
    for (int tn = 0; tn < 4; tn++)
#pragma unroll
      for (int tm = 0; tm < 4; tm++)
        acc[tn][tm] = MFMA16(af[tn], bfr[tm], acc[tn][tm]);
    __syncthreads();
  }

  int which = nblk >> 10;
  int cbase = nblk & 1023;
  const float* bias = (which == 0) ? bq : ((which == 1) ? bk : bv);

#pragma unroll
  for (int tm = 0; tm < 4; tm++) {
    int m = mblk + mh + tm*16 + l15;
    int b = m >> 11, s = m & 2047;
#pragma unroll
    for (int tn = 0; tn < 4; tn++) {
      int c = cbase + nh + tn*16 + 4*g;
      int head = c >> 6, d0 = c & 63;
      f32x4 bia = *(const f32x4*)(bias + c);
      short o[4];
#pragma unroll
      for (int r = 0; r < 4; r++) o[r] = f2bf(acc[tn][tm][r] + bia[r]);
      if (which == 2) {
        short* base = VT + ((size_t)(b*NH_ + head) * DH_ + d0) * S_ + s;
#pragma unroll
        for (int r = 0; r < 4; r++) base[(size_t)r * S_] = o[r];
      } else {
        short* dst = ((which == 0) ? Qws : Kws)
                   + ((size_t)(b*NH_ + head) * S_ + s) * DH_ + d0;
        bf16x4 o4 = {o[0], o[1], o[2], o[3]};
        *(bf16x4*)dst = o4;
      }
    }
  }
}

// 2-wave staging macros (lcalc): K tile 64 keys x 64 d (8KB).
#define STG_K(bufi, kt) do { \
    __builtin_amdgcn_global_load_lds(kSw + (size_t)(kt)*4096,        &Kb[bufi][w*2048],      16, 0, 0); \
    __builtin_amdgcn_global_load_lds(kSw + (size_t)(kt)*4096 + 512,  &Kb[bufi][w*2048+512],  16, 0, 0); \
    __builtin_amdgcn_global_load_lds(kSw + (size_t)(kt)*4096 + 1024, &Kb[bufi][w*2048+1024], 16, 0, 0); \
    __builtin_amdgcn_global_load_lds(kSw + (size_t)(kt)*4096 + 1536, &Kb[bufi][w*2048+1536], 16, 0, 0); \
  } while (0)

// ---------------- K2a: attn_lcalc — per-q-row 1/sum(exp) -------------------
__global__ __launch_bounds__(128, 2) void attn_lcalc(
    const short* __restrict__ Qws, const short* __restrict__ Kws,
    const float* __restrict__ mask, float* __restrict__ Linv) {
  __shared__ short Kb[2][4096];
  int bid = blockIdx.x;               // 1024 = 32 bh * 32 qt
  int bh = bid >> 5, qt = bid & 31;
  int tid = threadIdx.x;
  int w = tid >> 6, lane = tid & 63;
  int g = lane >> 4, l15 = lane & 15;
  int lr = lane >> 3, l7 = lane & 7;
  int b = bh >> 4;
  int qbase = qt * 64 + w * 32;

  const short* Kh = Kws + (size_t)bh * S_ * DH_;
  const float* mk = mask + b * S_;
  int sw = 8 * (l15 & 7);
  int swc = 8 * (l7 ^ lr);
  const short* kSw = Kh + (size_t)(w*32 + lr) * DH_ + swc;

  const short* qr0 = Qws + (size_t)bh * S_ * DH_ + (size_t)(qbase + l15) * DH_;
  const short* qr1 = qr0 + 16 * DH_;
  bf16x8 q0a = *(const bf16x8*)(qr0 + 8*g), q0b = *(const bf16x8*)(qr0 + 32 + 8*g);
  bf16x8 q1a = *(const bf16x8*)(qr1 + 8*g), q1b = *(const bf16x8*)(qr1 + 32 + 8*g);

  f32x4 ls0 = (f32x4){0.f,0.f,0.f,0.f}, ls1 = (f32x4){0.f,0.f,0.f,0.f};
  STG_K(0, 0);
  __syncthreads();
  int cur = 0;
  for (int kt = 0; kt < 32; kt++) {
    if (kt + 1 < 32) STG_K(cur ^ 1, kt + 1);
    const short* Kt = Kb[cur];
#pragma unroll
    for (int s0i = 0; s0i < 4; s0i++) {
      int s0 = s0i * 16;
      const short* kp = Kt + (s0 + l15) * 64;
      bf16x8 kf0 = *(const bf16x8*)(kp + ((8*g) ^ sw));
      bf16x8 kf1 = *(const bf16x8*)(kp + ((32 + 8*g) ^ sw));
      f32x4 a0 = (f32x4){0.f,0.f,0.f,0.f}, a1 = (f32x4){0.f,0.f,0.f,0.f};
      a0 = MFMA16(kf0, q0a, a0); a0 = MFMA16(kf1, q0b, a0);
      a1 = MFMA16(kf0, q1a, a1); a1 = MFMA16(kf1, q1b, a1);
      f32x4 mv = *(const f32x4*)(mk + kt*64 + s0 + 4*g);
#pragma unroll
      for (int r = 0; r < 4; r++) {
        ls0[r] += __expf(a0[r] * 0.125f * mv[r]);
        ls1[r] += __expf(a1[r] * 0.125f * mv[r]);
      }
    }
    __syncthreads();
    cur ^= 1;
  }
  float l0 = ls0[0]+ls0[1]+ls0[2]+ls0[3];
  float l1 = ls1[0]+ls1[1]+ls1[2]+ls1[3];
  l0 += __shfl_xor(l0, 16); l0 += __shfl_xor(l0, 32);
  l1 += __shfl_xor(l1, 16); l1 += __shfl_xor(l1, 32);
  if (lane < 16) {
    Linv[(size_t)bh * S_ + qbase + lane]      = 1.f / l0;
    Linv[(size_t)bh * S_ + qbase + 16 + lane] = 1.f / l1;
  }
}

// 4-wave staging macros (attn_main): each wave stages 16 rows (2x8) of 128B.
#define STG_K4(bufi, kt) do { \
    __builtin_amdgcn_global_load_lds(kS4 + (size_t)(kt)*4096,          &Kb[bufi][w*1024],      16, 0, 0); \
    __builtin_amdgcn_global_load_lds(kS4 + (size_t)(kt)*4096 + 8*DH_,  &Kb[bufi][w*1024+512],  16, 0, 0); \
  } while (0)
#define STG_V4(bufi, kt) do { \
    __builtin_amdgcn_global_load_lds(vS4 + (size_t)(kt)*64,            &Vb[bufi][w*1024],      16, 0, 0); \
    __builtin_amdgcn_global_load_lds(vS4 + (size_t)(kt)*64 + 8*(size_t)S_, &Vb[bufi][w*1024+512], 16, 0, 0); \
  } while (0)

// ---------------- K2b: attn_main — P to LDS, burst-write attn, PV ----------
// 4 waves x 16 q-rows. Keys processed in super-tiles of 256 (4 kt of 64);
// P (normalized, bf16) accumulates in LDS; after each super-tile, burst
// writes: one instr = 1KB contiguous within a q-row (64 lanes x 16B).
__global__ __launch_bounds__(256, 2) void attn_main(
    const short* __restrict__ Qws, const short* __restrict__ Kws,
    const short* __restrict__ VT, const float* __restrict__ mask,
    const float* __restrict__ Linv,
    float* __restrict__ ctx, float* __restrict__ attn) {
  __shared__ short Kb[2][4096];     // 16 KB
  __shared__ short Vb[2][4096];     // 16 KB
  __shared__ short Pb[64 * 256];    // 32 KB: [row 0..63][key 0..255] swizzled
  int bid = blockIdx.x;             // 1024 = 32 bh * 32 qt
  int bh = bid >> 5, qt = bid & 31;
  int tid = threadIdx.x;
  int w = tid >> 6, lane = tid & 63;
  int g = lane >> 4, l15 = lane & 15;
  int lhi = lane >> 3, l7 = lane & 7;
  int b = bh >> 4, h = bh & 15;
  int qbase = qt * 64 + w * 16;

  const short* Kh = Kws + (size_t)bh * S_ * DH_;
  const short* Vh = VT  + (size_t)bh * DH_ * S_;
  const float* mk = mask + b * S_;
  int sw = 8 * (l15 & 7);
  int swc = 8 * (l7 ^ lhi);
  const short* kS4 = Kh + (size_t)(w*16 + lhi) * DH_ + swc;
  const short* vS4 = Vh + (size_t)(w*16 + lhi) * S_  + swc;

  const short* qr0 = Qws + (size_t)bh * S_ * DH_ + (size_t)(qbase + l15) * DH_;
  bf16x8 q0a = *(const bf16x8*)(qr0 + 8*g), q0b = *(const bf16x8*)(qr0 + 32 + 8*g);
  float linv = Linv[(size_t)bh * S_ + qbase + l15];

  f32x4 oc[4];
#pragma unroll
  for (int tv = 0; tv < 4; tv++) oc[tv] = (f32x4){0.f,0.f,0.f,0.f};

  int prow = w*16 + l15;            // this lane's P row (q-row local)
  float* ablk = attn + ((size_t)bh * S_ + qt*64) * (size_t)S_;

  STG_K4(0, 0); STG_V4(0, 0);
  __syncthreads();
  int cur = 0;
  for (int st = 0; st < 8; st++) {
#pragma unroll
    for (int j = 0; j < 4; j++) {
      int kt = st*4 + j;
      if (kt + 1 < 32) { STG_K4(cur ^ 1, kt + 1); STG_V4(cur ^ 1, kt + 1); }
      const short* Kt = Kb[cur];
      const short* Vt = Vb[cur];
#pragma unroll
      for (int khi = 0; khi < 2; khi++) {
        int kh = khi * 32;
        bf16x8 pa;
#pragma unroll
        for (int half = 0; half < 2; half++) {
          int s0 = kh + half * 16;
          const short* kp = Kt + (s0 + l15) * 64;
          bf16x8 kf0 = *(const bf16x8*)(kp + ((8*g) ^ sw));
          bf16x8 kf1 = *(const bf16x8*)(kp + ((32 + 8*g) ^ sw));
          f32x4 a0 = (f32x4){0.f,0.f,0.f,0.f};
          a0 = MFMA16(kf0, q0a, a0); a0 = MFMA16(kf1, q0b, a0);
          f32x4 mv = *(const f32x4*)(mk + kt*64 + s0 + 4*g);
          bf16x4 p4;
#pragma unroll
          for (int r = 0; r < 4; r++) {
            float p = __expf(a0[r] * 0.125f * mv[r]) * linv;
            short pb = f2bf(p);
            p4[r] = pb;
            pa[half*4 + r] = pb;
          }
          // P-LDS write: row = prow, local key lk (4 consecutive, granule-XOR)
          int lk = j*64 + s0 + 4*g;
          int ps = prow*256 + ((lk & 7) | ((((lk >> 3) ^ (prow & 7))) << 3));
          *(bf16x4*)(&Pb[ps]) = p4;
        }
#pragma unroll
        for (int tv = 0; tv < 4; tv++) {
          const short* vp = Vt + (tv*16 + l15) * 64;
          bf16x4 va = *(const bf16x4*)(vp + ((kh + 4*g) ^ sw));
          bf16x4 vb2 = *(const bf16x4*)(vp + ((kh + 16 + 4*g) ^ sw));
          bf16x8 vf = {va[0],va[1],va[2],va[3], vb2[0],vb2[1],vb2[2],vb2[3]};
          oc[tv] = MFMA16(pa, vf, oc[tv]);
        }
      }
      __syncthreads();
      cur ^= 1;
    }
    // ---- burst-write this super-tile: wave w writes rows w*16..w*16+15 ----
#pragma unroll
    for (int i = 0; i < 16; i++) {
      int row = w*16 + i;
      int lk = 4 * lane;
      int ps = row*256 + ((lk & 7) | ((((lk >> 3) ^ (row & 7))) << 3));
      bf16x4 pv4 = *(const bf16x4*)(&Pb[ps]);
      f32x4 o = { bf2f(pv4[0]), bf2f(pv4[1]), bf2f(pv4[2]), bf2f(pv4[3]) };
      *(f32x4*)(ablk + (size_t)row * S_ + st*256 + lk) = o;
    }
    __syncthreads();
  }

  // ctx: lane writes q = qbase + 4g + r, d = tv*16 + l15
#pragma unroll
  for (int tv = 0; tv < 4; tv++) {
#pragma unroll
    for (int r = 0; r < 4; r++) {
      int q = qbase + 4*g + r;
      ctx[((size_t)b * S_ + q) * H_ + h * DH_ + tv*16 + l15] = oc[tv][r];
    }
  }
}

// ---------------- host ----------------------------------------------------
extern "C" void kernel_launch(void* const* d_in, const int* in_sizes, int n_in,
                              void* d_out, int out_size, void* d_ws, size_t ws_size,
                              hipStream_t stream) {
  const float* q    = (const float*)d_in[0];
  const float* mask = (const float*)d_in[1];
  const float* Wq   = (const float*)d_in[2];
  const float* bq   = (const float*)d_in[3];
  const float* Wk   = (const float*)d_in[4];
  const float* bk   = (const float*)d_in[5];
  const float* Wv   = (const float*)d_in[6];
  const float* bv   = (const float*)d_in[7];

  float* ctx  = (float*)d_out;
  float* attn = ctx + (size_t)B_ * S_ * H_;

  short* qb  = (short*)d_ws;                          // 8 MB
  short* Wt  = qb  + (size_t)M_ * K_;                 // 6 MB
  short* Qws = Wt  + (size_t)N3_ * K_;                // 8 MB
  short* Kws = Qws + (size_t)B_ * NH_ * S_ * DH_;     // 8 MB
  short* VT  = Kws + (size_t)B_ * NH_ * S_ * DH_;     // 8 MB
  float* Linv = (float*)(VT + (size_t)B_ * NH_ * S_ * DH_);  // 256 KB

  convert_q<<<(M_ * K_) / (256 * 4), 256, 0, stream>>>(q, qb);
  transpose_w<<<dim3(32, 32, 3), dim3(32, 8), 0, stream>>>(Wq, Wk, Wv, Wt);
  qkv_gemm<<<768, 256, 0, stream>>>(qb, Wt, bq, bk, bv, Qws, Kws, VT);
  attn_lcalc<<<1024, 128, 0, stream>>>(Qws, Kws, mask, Linv);
  attn_main<<<1024, 256, 0, stream>>>(Qws, Kws, VT, mask, Linv, ctx, attn);
}

// Round 6
// 211.274 us; speedup vs baseline: 1.4109x; 1.2450x over previous
//
#include <hip/hip_runtime.h>
#include <hip/hip_bf16.h>

#define B_ 2
#define S_ 2048
#define H_ 1024
#define NH_ 16
#define DH_ 64
#define M_ (B_*S_)      // 4096 rows of q
#define N3_ (3*H_)      // 3072 fused output cols
#define K_ H_           // 1024 reduction dim

typedef __attribute__((ext_vector_type(8))) short bf16x8;
typedef __attribute__((ext_vector_type(4))) short bf16x4;
typedef __attribute__((ext_vector_type(4))) float f32x4;

__device__ __forceinline__ short f2bf(float f) {
  union { float fv; unsigned u; } v; v.fv = f;
  return (short)((v.u + 0x7FFFu + ((v.u >> 16) & 1u)) >> 16);
}
__device__ __forceinline__ float bf2f(short s) {
  union { unsigned u; float fv; } v; v.u = ((unsigned)(unsigned short)s) << 16;
  return v.fv;
}

#define MFMA16(a,b,c) __builtin_amdgcn_mfma_f32_16x16x32_bf16((a),(b),(c),0,0,0)

// ---------------- K0a: convert q fp32 -> bf16 ------------------------------
__global__ __launch_bounds__(256) void convert_q(const float* __restrict__ q,
                                                 short* __restrict__ qb) {
  int i = blockIdx.x * blockDim.x + threadIdx.x;
  f32x4 v = ((const f32x4*)q)[i];
  bf16x4 o = { f2bf(v[0]), f2bf(v[1]), f2bf(v[2]), f2bf(v[3]) };
  ((bf16x4*)qb)[i] = o;
}

// ---------------- K0b: transpose+convert W [k][n] fp32 -> Wt [3][n][k] bf16 -
__global__ __launch_bounds__(256) void transpose_w(const float* __restrict__ Wq,
                                                   const float* __restrict__ Wk,
                                                   const float* __restrict__ Wv,
                                                   short* __restrict__ Wt) {
  __shared__ float tile[32][33];
  int w = blockIdx.z;
  const float* W = (w == 0) ? Wq : ((w == 1) ? Wk : Wv);
  int n0 = blockIdx.x * 32, k0 = blockIdx.y * 32;
  int tx = threadIdx.x, ty = threadIdx.y;   // block (32,8)
  for (int i = 0; i < 4; i++)
    tile[ty + 8*i][tx] = W[(size_t)(k0 + ty + 8*i) * H_ + n0 + tx];
  __syncthreads();
  for (int i = 0; i < 4; i++)
    Wt[(size_t)w * H_ * H_ + (size_t)(n0 + ty + 8*i) * H_ + k0 + tx] =
        f2bf(tile[tx][ty + 8*i]);
}

// ---------------- K1: QKV projection GEMM (m97 structure) ------------------
__global__ __launch_bounds__(256) void qkv_gemm(
    const short* __restrict__ qb,   // [4096][1024]
    const short* __restrict__ Wt,   // [3072][1024]
    const float* __restrict__ bq, const float* __restrict__ bk,
    const float* __restrict__ bv,
    short* __restrict__ Qws, short* __restrict__ Kws, short* __restrict__ VT) {
  __shared__ short Wtile[128 * 32];
  __shared__ short Qtile[128 * 32];

  int bidx = blockIdx.x;              // 768 = 32 mtiles * 24 ntiles
  int mt = bidx & 31, nt = bidx >> 5;
  int t = threadIdx.x;
  int wave = t >> 6, lane = t & 63;
  int g = lane >> 4, l15 = lane & 15;
  int nh = (wave & 1) * 64, mh = (wave >> 1) * 64;
  int mblk = mt * 128, nblk = nt * 128;

  int srow = t >> 2, ssub = t & 3;
  const short* wsrc = Wt + (size_t)(nblk + srow) * K_ + ssub * 8;
  const short* qsrc = qb + (size_t)(mblk + srow) * K_ + ssub * 8;
  short* wdst0 = Wtile + wave * 512;
  short* qdst0 = Qtile + wave * 512;

  f32x4 acc[4][4];
#pragma unroll
  for (int i = 0; i < 4; i++)
#pragma unroll
    for (int j = 0; j < 4; j++) acc[i][j] = (f32x4){0.f,0.f,0.f,0.f};

  for (int k0 = 0; k0 < K_; k0 += 32) {
    __builtin_amdgcn_global_load_lds(wsrc + k0,         wdst0,         16, 0, 0);
    __builtin_amdgcn_global_load_lds(wsrc + 64*K_ + k0, wdst0 + 64*32, 16, 0, 0);
    __builtin_amdgcn_global_load_lds(qsrc + k0,         qdst0,         16, 0, 0);
    __builtin_amdgcn_global_load_lds(qsrc + 64*K_ + k0, qdst0 + 64*32, 16, 0, 0);
    __syncthreads();
    bf16x8 af[4], bfr[4];
#pragma unroll
    for (int tn = 0; tn < 4; tn++)
      af[tn] = *(const bf16x8*)(Wtile + (nh + tn*16 + l15) * 32 + g * 8);
#pragma unroll
    for (int tm = 0; tm < 4; tm++)
      bfr[tm] = *(const bf16x8*)(Qtile + (mh + tm*16 + l15) * 32 + g * 8);
#pragma unroll
    for (int tn = 0; tn < 4; tn++)
#pragma unroll
      for (int tm = 0; tm < 4; tm++)
        acc[tn][tm] = MFMA16(af[tn], bfr[tm], acc[tn][tm]);
    __syncthreads();
  }

  int which = nblk >> 10;
  int cbase = nblk & 1023;
  const float* bias = (which == 0) ? bq : ((which == 1) ? bk : bv);

#pragma unroll
  for (int tm = 0; tm < 4; tm++) {
    int m = mblk + mh + tm*16 + l15;
    int b = m >> 11, s = m & 2047;
#pragma unroll
    for (int tn = 0; tn < 4; tn++) {
      int c = cbase + nh + tn*16 + 4*g;
      int head = c >> 6, d0 = c & 63;
      f32x4 bia = *(const f32x4*)(bias + c);
      short o[4];
#pragma unroll
      for (int r = 0; r < 4; r++) o[r] = f2bf(acc[tn][tm][r] + bia[r]);
      if (which == 2) {
        short* base = VT + ((size_t)(b*NH_ + head) * DH_ + d0) * S_ + s;
#pragma unroll
        for (int r = 0; r < 4; r++) base[(size_t)r * S_] = o[r];
      } else {
        short* dst = ((which == 0) ? Qws : Kws)
                   + ((size_t)(b*NH_ + head) * S_ + s) * DH_ + d0;
        bf16x4 o4 = {o[0], o[1], o[2], o[3]};
        *(bf16x4*)dst = o4;
      }
    }
  }
}

// 2-wave staging macros (lcalc): K tile 64 keys x 64 d (8KB).
#define STG_K(bufi, kt) do { \
    __builtin_amdgcn_global_load_lds(kSw + (size_t)(kt)*4096,        &Kb[bufi][w*2048],      16, 0, 0); \
    __builtin_amdgcn_global_load_lds(kSw + (size_t)(kt)*4096 + 512,  &Kb[bufi][w*2048+512],  16, 0, 0); \
    __builtin_amdgcn_global_load_lds(kSw + (size_t)(kt)*4096 + 1024, &Kb[bufi][w*2048+1024], 16, 0, 0); \
    __builtin_amdgcn_global_load_lds(kSw + (size_t)(kt)*4096 + 1536, &Kb[bufi][w*2048+1536], 16, 0, 0); \
  } while (0)

// ---------------- K2a: attn_lcalc — per-q-row 1/sum(exp) -------------------
__global__ __launch_bounds__(128, 2) void attn_lcalc(
    const short* __restrict__ Qws, const short* __restrict__ Kws,
    const float* __restrict__ mask, float* __restrict__ Linv) {
  __shared__ short Kb[2][4096];
  int bid0 = blockIdx.x;              // 1024 = 32 bh * 32 qt
  int bid = (bid0 & 7) * 128 + (bid0 >> 3);   // XCD swizzle: 4 bh per XCD
  int bh = bid >> 5, qt = bid & 31;
  int tid = threadIdx.x;
  int w = tid >> 6, lane = tid & 63;
  int g = lane >> 4, l15 = lane & 15;
  int lr = lane >> 3, l7 = lane & 7;
  int b = bh >> 4;
  int qbase = qt * 64 + w * 32;

  const short* Kh = Kws + (size_t)bh * S_ * DH_;
  const float* mk = mask + b * S_;
  int sw = 8 * (l15 & 7);
  int swc = 8 * (l7 ^ lr);
  const short* kSw = Kh + (size_t)(w*32 + lr) * DH_ + swc;

  const short* qr0 = Qws + (size_t)bh * S_ * DH_ + (size_t)(qbase + l15) * DH_;
  const short* qr1 = qr0 + 16 * DH_;
  bf16x8 q0a = *(const bf16x8*)(qr0 + 8*g), q0b = *(const bf16x8*)(qr0 + 32 + 8*g);
  bf16x8 q1a = *(const bf16x8*)(qr1 + 8*g), q1b = *(const bf16x8*)(qr1 + 32 + 8*g);

  f32x4 ls0 = (f32x4){0.f,0.f,0.f,0.f}, ls1 = (f32x4){0.f,0.f,0.f,0.f};
  STG_K(0, 0);
  __syncthreads();
  int cur = 0;
  for (int kt = 0; kt < 32; kt++) {
    if (kt + 1 < 32) STG_K(cur ^ 1, kt + 1);
    const short* Kt = Kb[cur];
#pragma unroll
    for (int s0i = 0; s0i < 4; s0i++) {
      int s0 = s0i * 16;
      const short* kp = Kt + (s0 + l15) * 64;
      bf16x8 kf0 = *(const bf16x8*)(kp + ((8*g) ^ sw));
      bf16x8 kf1 = *(const bf16x8*)(kp + ((32 + 8*g) ^ sw));
      f32x4 a0 = (f32x4){0.f,0.f,0.f,0.f}, a1 = (f32x4){0.f,0.f,0.f,0.f};
      a0 = MFMA16(kf0, q0a, a0); a0 = MFMA16(kf1, q0b, a0);
      a1 = MFMA16(kf0, q1a, a1); a1 = MFMA16(kf1, q1b, a1);
      f32x4 mv = *(const f32x4*)(mk + kt*64 + s0 + 4*g);
#pragma unroll
      for (int r = 0; r < 4; r++) {
        ls0[r] += __expf(a0[r] * 0.125f * mv[r]);
        ls1[r] += __expf(a1[r] * 0.125f * mv[r]);
      }
    }
    __syncthreads();
    cur ^= 1;
  }
  float l0 = ls0[0]+ls0[1]+ls0[2]+ls0[3];
  float l1 = ls1[0]+ls1[1]+ls1[2]+ls1[3];
  l0 += __shfl_xor(l0, 16); l0 += __shfl_xor(l0, 32);
  l1 += __shfl_xor(l1, 16); l1 += __shfl_xor(l1, 32);
  if (lane < 16) {
    Linv[(size_t)bh * S_ + qbase + lane]      = 1.f / l0;
    Linv[(size_t)bh * S_ + qbase + 16 + lane] = 1.f / l1;
  }
}

// 4-wave staging macros (attn_main): each wave stages 16 rows (2x8) of 128B.
#define STG_K4(bufi, kt) do { \
    __builtin_amdgcn_global_load_lds(kS4 + (size_t)(kt)*4096,          &Kb[bufi][w*1024],      16, 0, 0); \
    __builtin_amdgcn_global_load_lds(kS4 + (size_t)(kt)*4096 + 8*DH_,  &Kb[bufi][w*1024+512],  16, 0, 0); \
  } while (0)
#define STG_V4(bufi, kt) do { \
    __builtin_amdgcn_global_load_lds(vS4 + (size_t)(kt)*64,            &Vb[bufi][w*1024],      16, 0, 0); \
    __builtin_amdgcn_global_load_lds(vS4 + (size_t)(kt)*64 + 8*(size_t)S_, &Vb[bufi][w*1024+512], 16, 0, 0); \
  } while (0)

// ---------------- K2b: attn_main — pipelined P-burst, PV -------------------
// 4 waves x 16 q-rows. Super-tile = 128 keys (2 kt). P (normalized bf16)
// written to Pb[st&1]; burst stores for super-tile st-1 are interleaved into
// the compute of kt (4 NT store instrs each kt). No extra barriers: each
// wave bursts only its own rows; per-wave LDS ops are in-order.
// P swizzle: 8B granule gi -> gi ^ ((row&7)<<2): writes & reads 2-way (free).
__global__ __launch_bounds__(256, 2) void attn_main(
    const short* __restrict__ Qws, const short* __restrict__ Kws,
    const short* __restrict__ VT, const float* __restrict__ mask,
    const float* __restrict__ Linv,
    float* __restrict__ ctx, float* __restrict__ attn) {
  __shared__ short Kb[2][4096];     // 16 KB
  __shared__ short Vb[2][4096];     // 16 KB
  __shared__ short Pb[2][64 * 128]; // 32 KB: [half][row 0..63][key 0..127]
  int bid0 = blockIdx.x;            // 1024 = 32 bh * 32 qt
  int bid = (bid0 & 7) * 128 + (bid0 >> 3);   // XCD swizzle: 4 bh per XCD
  int bh = bid >> 5, qt = bid & 31;
  int tid = threadIdx.x;
  int w = tid >> 6, lane = tid & 63;
  int g = lane >> 4, l15 = lane & 15;
  int lhi = lane >> 3, l7 = lane & 7;
  int l31 = lane & 31, lh = lane >> 5;
  int b = bh >> 4, h = bh & 15;
  int qbase = qt * 64 + w * 16;

  const short* Kh = Kws + (size_t)bh * S_ * DH_;
  const short* Vh = VT  + (size_t)bh * DH_ * S_;
  const float* mk = mask + b * S_;
  int sw = 8 * (l15 & 7);
  int swc = 8 * (l7 ^ lhi);
  const short* kS4 = Kh + (size_t)(w*16 + lhi) * DH_ + swc;
  const short* vS4 = Vh + (size_t)(w*16 + lhi) * S_  + swc;

  const short* qr0 = Qws + (size_t)bh * S_ * DH_ + (size_t)(qbase + l15) * DH_;
  bf16x8 q0a = *(const bf16x8*)(qr0 + 8*g), q0b = *(const bf16x8*)(qr0 + 32 + 8*g);
  float linv = Linv[(size_t)bh * S_ + qbase + l15];

  f32x4 oc[4];
#pragma unroll
  for (int tv = 0; tv < 4; tv++) oc[tv] = (f32x4){0.f,0.f,0.f,0.f};

  int prow = w*16 + l15;            // this lane's P row (q-row local)
  float* ablk = attn + ((size_t)bh * S_ + qt*64) * (size_t)S_;

  STG_K4(0, 0); STG_V4(0, 0);
  __syncthreads();
  int cur = 0;
  for (int kt = 0; kt < 32; kt++) {
    if (kt + 1 < 32) { STG_K4(cur ^ 1, kt + 1); STG_V4(cur ^ 1, kt + 1); }
    // ---- interleaved burst: half of super-tile (kt>>1)-1 ----
    if (kt >= 2) {
      int pst = (kt >> 1) - 1;
      const short* Pp = Pb[pst & 1];
      int rbase = w*16 + 8*(kt & 1);
#pragma unroll
      for (int i = 0; i < 4; i++) {
        int row = rbase + 2*i + lh;
        int gi2 = l31 ^ ((row & 7) << 2);
        bf16x4 pv4 = *(const bf16x4*)(&Pp[row*128 + (gi2 << 2)]);
        f32x4 o = { bf2f(pv4[0]), bf2f(pv4[1]), bf2f(pv4[2]), bf2f(pv4[3]) };
        __builtin_nontemporal_store(o,
            (f32x4*)(ablk + (size_t)row * S_ + pst*128 + 4*l31));
      }
    }
    // ---- compute kt: scores -> P (LDS) + PV MFMA ----
    const short* Kt = Kb[cur];
    const short* Vt = Vb[cur];
    short* Pcur = Pb[(kt >> 1) & 1];
#pragma unroll
    for (int khi = 0; khi < 2; khi++) {
      int kh = khi * 32;
      bf16x8 pa;
#pragma unroll
      for (int half = 0; half < 2; half++) {
        int s0 = kh + half * 16;
        const short* kp = Kt + (s0 + l15) * 64;
        bf16x8 kf0 = *(const bf16x8*)(kp + ((8*g) ^ sw));
        bf16x8 kf1 = *(const bf16x8*)(kp + ((32 + 8*g) ^ sw));
        f32x4 a0 = (f32x4){0.f,0.f,0.f,0.f};
        a0 = MFMA16(kf0, q0a, a0); a0 = MFMA16(kf1, q0b, a0);
        f32x4 mv = *(const f32x4*)(mk + kt*64 + s0 + 4*g);
        bf16x4 p4;
#pragma unroll
        for (int r = 0; r < 4; r++) {
          float p = __expf(a0[r] * 0.125f * mv[r]) * linv;
          short pb = f2bf(p);
          p4[r] = pb;
          pa[half*4 + r] = pb;
        }
        int lk = (kt & 1)*64 + s0 + 4*g;
        int gi = (lk >> 2) ^ ((prow & 7) << 2);
        *(bf16x4*)(&Pcur[prow*128 + (gi << 2)]) = p4;
      }
#pragma unroll
      for (int tv = 0; tv < 4; tv++) {
        const short* vp = Vt + (tv*16 + l15) * 64;
        bf16x4 va = *(const bf16x4*)(vp + ((kh + 4*g) ^ sw));
        bf16x4 vb2 = *(const bf16x4*)(vp + ((kh + 16 + 4*g) ^ sw));
        bf16x8 vf = {va[0],va[1],va[2],va[3], vb2[0],vb2[1],vb2[2],vb2[3]};
        oc[tv] = MFMA16(pa, vf, oc[tv]);
      }
    }
    __syncthreads();
    cur ^= 1;
  }

  // ---- tail flush: super-tile 15 (all 16 rows) ----
  {
    const short* Pp = Pb[1];
#pragma unroll
    for (int i = 0; i < 8; i++) {
      int row = w*16 + 2*i + lh;
      int gi2 = l31 ^ ((row & 7) << 2);
      bf16x4 pv4 = *(const bf16x4*)(&Pp[row*128 + (gi2 << 2)]);
      f32x4 o = { bf2f(pv4[0]), bf2f(pv4[1]), bf2f(pv4[2]), bf2f(pv4[3]) };
      __builtin_nontemporal_store(o,
          (f32x4*)(ablk + (size_t)row * S_ + 15*128 + 4*l31));
    }
  }

  // ctx: lane writes q = qbase + 4g + r, d = tv*16 + l15
#pragma unroll
  for (int tv = 0; tv < 4; tv++) {
#pragma unroll
    for (int r = 0; r < 4; r++) {
      int q = qbase + 4*g + r;
      ctx[((size_t)b * S_ + q) * H_ + h * DH_ + tv*16 + l15] = oc[tv][r];
    }
  }
}

// ---------------- host ----------------------------------------------------
extern "C" void kernel_launch(void* const* d_in, const int* in_sizes, int n_in,
                              void* d_out, int out_size, void* d_ws, size_t ws_size,
                              hipStream_t stream) {
  const float* q    = (const float*)d_in[0];
  const float* mask = (const float*)d_in[1];
  const float* Wq   = (const float*)d_in[2];
  const float* bq   = (const float*)d_in[3];
  const float* Wk   = (const float*)d_in[4];
  const float* bk   = (const float*)d_in[5];
  const float* Wv   = (const float*)d_in[6];
  const float* bv   = (const float*)d_in[7];

  float* ctx  = (float*)d_out;
  float* attn = ctx + (size_t)B_ * S_ * H_;

  short* qb  = (short*)d_ws;                          // 8 MB
  short* Wt  = qb  + (size_t)M_ * K_;                 // 6 MB
  short* Qws = Wt  + (size_t)N3_ * K_;                // 8 MB
  short* Kws = Qws + (size_t)B_ * NH_ * S_ * DH_;     // 8 MB
  short* VT  = Kws + (size_t)B_ * NH_ * S_ * DH_;     // 8 MB
  float* Linv = (float*)(VT + (size_t)B_ * NH_ * S_ * DH_);  // 256 KB

  convert_q<<<(M_ * K_) / (256 * 4), 256, 0, stream>>>(q, qb);
  transpose_w<<<dim3(32, 32, 3), dim3(32, 8), 0, stream>>>(Wq, Wk, Wv, Wt);
  qkv_gemm<<<768, 256, 0, stream>>>(qb, Wt, bq, bk, bv, Qws, Kws, VT);
  attn_lcalc<<<1024, 128, 0, stream>>>(Qws, Kws, mask, Linv);
  attn_main<<<1024, 256, 0, stream>>>(Qws, Kws, VT, mask, Linv, ctx, attn);
}